// Round 12
// baseline (81.334 us; speedup 1.0000x reference)
//
#include <hip/hip_runtime.h>
#include <hip/hip_fp16.h>
#include <cstdint>

#define B_   8
#define C_   256
#define H_   64
#define W_   64
#define HW_  4096
#define NH_  8
#define NP_  4
#define DH_  32

typedef unsigned int u32;
typedef unsigned short u16;
typedef __attribute__((ext_vector_type(8))) short bf16x8;
typedef __attribute__((ext_vector_type(4))) float f32x4;
typedef __attribute__((ext_vector_type(4))) u32 u32x4;
typedef __attribute__((address_space(3))) u32 as3_u32;
typedef __attribute__((address_space(1))) u32 as1_u32;

__device__ __forceinline__ u16 f2bf(float f) {
  u32 u = __builtin_bit_cast(u32, f);
  return (u16)((u + 0x7FFFu + ((u >> 16) & 1u)) >> 16);
}
__device__ __forceinline__ float bflo(u32 v) { return __builtin_bit_cast(float, v << 16); }
__device__ __forceinline__ float bfhi(u32 v) { return __builtin_bit_cast(float, v & 0xFFFF0000u); }

// ---------------------------------------------------------------------------
// Kernel 1a: key transpose -> bf16; w_proj -> bf16; w_off -> bf16 slots.
// blocks [0,4096): transpose; [4096,4160): w_proj; [4160,4184): w_off slots.
// w_off slot layout: [col 0..95][kc 0..31] 16B (8 channels kc*8.. packed bf16).
// ---------------------------------------------------------------------------
__global__ __launch_bounds__(256) void k_trans_conv(const float* __restrict__ key,
                                                    const float* __restrict__ w_proj,
                                                    const float* __restrict__ w_off,
                                                    u32* __restrict__ key_t2,
                                                    uint2* __restrict__ wproj_bf,
                                                    u32x4* __restrict__ woff_slots) {
  __shared__ float tile[32 * 65];
  const int bid = blockIdx.x;
  const int t = threadIdx.x;

  if (bid < 4096) {
    const int g = bid >> 6;
    const int hw0 = (bid & 63) << 6;
    const float* kg = key + (size_t)g * DH_ * HW_ + hw0;
    #pragma unroll
    for (int k = 0; k < 8; ++k) {
      int idx = t + k * 256;
      int d = idx >> 6, j = idx & 63;
      tile[d * 65 + j] = kg[d * HW_ + j];
    }
    __syncthreads();
    u32* kt = key_t2 + ((size_t)g * HW_ + hw0) * 16;
    #pragma unroll
    for (int k = 0; k < 4; ++k) {
      int idx = t + k * 256;
      int j = idx >> 4, dp = idx & 15;
      u32 v = (u32)f2bf(tile[(2 * dp) * 65 + j]) | ((u32)f2bf(tile[(2 * dp + 1) * 65 + j]) << 16);
      kt[j * 16 + dp] = v;
    }
  } else if (bid < 4160) {
    int i = (bid - 4096) * 256 + t;
    float4 v = ((const float4*)w_proj)[i];
    uint2 o;
    o.x = (u32)f2bf(v.x) | ((u32)f2bf(v.y) << 16);
    o.y = (u32)f2bf(v.z) | ((u32)f2bf(v.w) << 16);
    wproj_bf[i] = o;
  } else {
    // w_off (96x256 f32) -> bf16 16B slots [col][kc], linear
    int m = (bid - 4160) * 256 + t;      // 0..6143 = col*32 + kc
    const float4* w4 = (const float4*)w_off;
    float4 lo = w4[m * 2];
    float4 hi = w4[m * 2 + 1];
    u32x4 v;
    v.x = (u32)f2bf(lo.x) | ((u32)f2bf(lo.y) << 16);
    v.y = (u32)f2bf(lo.z) | ((u32)f2bf(lo.w) << 16);
    v.z = (u32)f2bf(hi.x) | ((u32)f2bf(hi.y) << 16);
    v.w = (u32)f2bf(hi.z) | ((u32)f2bf(hi.w) << 16);
    woff_slots[m] = v;
  }
}

// ---------------------------------------------------------------------------
// Kernel 1b: offsets GEMM. A staged in 32KB LDS (conflict-free b128 writes),
// B fragments read DIRECTLY from global bf16 slots (48KB, L2-resident).
// LDS 32KB -> 4 blocks/CU. Epilogue: softmax + f16 weights, stride-97 LDS,
// [g][p][hw] coalesced output layout.
// ---------------------------------------------------------------------------
__global__ __launch_bounds__(256) void k_offsets_mfma(const float* __restrict__ query,
                                                      const u16* __restrict__ woff_slots,
                                                      const float* __restrict__ b_off,
                                                      uint2* __restrict__ wpk,
                                                      u32* __restrict__ idx4) {
  __shared__ char smem[32768];
  const int t = threadIdx.x, l = t & 63, w = t >> 6;
  const int lr = l & 15, lq = l >> 4;
  const int r0 = blockIdx.x * 64;
  const int b  = r0 >> 12;
  const int hw0 = r0 & 4095;

  // ---- A stage: 2048 slots (kc 0..31 x row 0..63), 8 slots/thread ----
  {
    const float* qb = query + ((size_t)b * 256) * 4096 + hw0;
    #pragma unroll
    for (int s = 0; s < 8; ++s) {
      int sid = t + s * 256;             // kc*64 + i ; wave-uniform kc, i=lane
      int kc = sid >> 6, i = sid & 63;
      const float* src = qb + (size_t)(kc * 8) * 4096 + i;
      u32x4 v;
      #pragma unroll
      for (int m = 0; m < 4; ++m) {
        float c0 = src[(size_t)(2 * m) * 4096];
        float c1 = src[(size_t)(2 * m + 1) * 4096];
        ((u32*)&v)[m] = (u32)f2bf(c0) | ((u32)f2bf(c1) << 16);
      }
      *(u32x4*)(smem + sid * 16) = v;    // ds_write_b128, conflict-free
    }
  }
  __syncthreads();

  // ---- MFMA: wave w = rows w*16..w*16+15; acc 1x6; B fragments from global ----
  f32x4 acc[6];
  #pragma unroll
  for (int n = 0; n < 6; ++n) acc[n] = (f32x4){0.f, 0.f, 0.f, 0.f};

  #pragma unroll
  for (int step = 0; step < 8; ++step) {
    const int kc = step * 4 + lq;
    bf16x8 af = *(const bf16x8*)(smem + (kc * 64 + w * 16 + lr) * 16);
    #pragma unroll
    for (int n = 0; n < 6; ++n) {
      int col = n * 16 + lr;
      bf16x8 bfr = *(const bf16x8*)(woff_slots + (size_t)(col * 32 + kc) * 8);
      acc[n] = __builtin_amdgcn_mfma_f32_16x16x32_bf16(af, bfr, acc[n], 0, 0, 0);
    }
  }
  __syncthreads();

  // ---- epilogue: acc -> LDS [row][o] stride 97 (conflict-free), + bias ----
  float* epi = (float*)smem;
  #pragma unroll
  for (int n = 0; n < 6; ++n) {
    int o = n * 16 + lr;
    float bo = b_off[o];
    int row = w * 16 + lq * 4;
    #pragma unroll
    for (int r = 0; r < 4; ++r)
      epi[(row + r) * 97 + o] = acc[n][r] + bo;
  }
  __syncthreads();

  // ---- softmax + f16-packed weights/indices: 64 rows x 8 heads ----
  #pragma unroll
  for (int k = 0; k < 2; ++k) {
    int task = t + k * 256;
    int row = task & 63, head = task >> 6;
    const float* o = epi + row * 97 + head * 12;
    float ox[NP_], oy[NP_], lg[NP_];
    #pragma unroll
    for (int p = 0; p < NP_; ++p) {
      ox[p] = o[p * 3 + 0];
      oy[p] = o[p * 3 + 1];
      lg[p] = o[p * 3 + 2];
    }
    float mx = fmaxf(fmaxf(lg[0], lg[1]), fmaxf(lg[2], lg[3]));
    float e[NP_];
    float s = 0.f;
    #pragma unroll
    for (int p = 0; p < NP_; ++p) { e[p] = expf(lg[p] - mx); s += e[p]; }
    float inv = 1.f / s;

    int hw = (r0 + row) & 4095;
    float wq = (float)(hw & 63);
    float hq = (float)(hw >> 6);
    int g = b * NH_ + head;
    #pragma unroll
    for (int p = 0; p < NP_; ++p) {
      float wt = e[p] * inv;
      float x = wq + ox[p] * 3.15f;
      float y = hq + oy[p] * 3.15f;
      float x0f = floorf(x), y0f = floorf(y);
      int ix0 = (int)x0f, iy0 = (int)y0f;
      int ix1 = ix0 + 1, iy1 = iy0 + 1;
      float fx = x - x0f, fy = y - y0f;
      float gx0 = 1.f - fx, gy0 = 1.f - fy;

      bool vx0 = (ix0 >= 0) & (ix0 <= W_ - 1);
      bool vx1 = (ix1 >= 0) & (ix1 <= W_ - 1);
      bool vy0 = (iy0 >= 0) & (iy0 <= H_ - 1);
      bool vy1 = (iy1 >= 0) & (iy1 <= H_ - 1);
      int cx0 = min(max(ix0, 0), W_ - 1), cx1 = min(max(ix1, 0), W_ - 1);
      int cy0 = min(max(iy0, 0), H_ - 1), cy1 = min(max(iy1, 0), H_ - 1);

      float w00 = wt * gx0 * gy0 * ((vx0 & vy0) ? 1.f : 0.f);
      float w01 = wt * fx  * gy0 * ((vx1 & vy0) ? 1.f : 0.f);
      float w10 = wt * gx0 * fy  * ((vx0 & vy1) ? 1.f : 0.f);
      float w11 = wt * fx  * fy  * ((vx1 & vy1) ? 1.f : 0.f);

      __half2 h01 = __floats2half2_rn(w00, w01);
      __half2 h23 = __floats2half2_rn(w10, w11);
      uint2 pk;
      pk.x = *(u32*)&h01;
      pk.y = *(u32*)&h23;
      size_t idx = (((size_t)g * NP_ + p) << 12) + hw;   // [g][p][hw] coalesced
      wpk[idx]  = pk;
      idx4[idx] = (u32)cx0 | ((u32)cx1 << 6) | ((u32)cy0 << 12) | ((u32)cy1 << 18);
    }
  }
}

// ---------------------------------------------------------------------------
// Kernel 2: bilinear gather + weighted sum (f16 weights, [g][p][hw] params).
// ---------------------------------------------------------------------------
__global__ __launch_bounds__(256) void k_sample(const uint2* __restrict__ wpk,
                                                const u32* __restrict__ idx4,
                                                const u32* __restrict__ key_t2,
                                                u32* __restrict__ feat2) {
  const int t = threadIdx.x;
  const int hwid = blockIdx.x * 2 + (t >> 7);
  const int b = hwid >> 12;
  const int hw = hwid & 4095;
  const int c2 = t & 127;
  const int head = c2 >> 4, dp = c2 & 15;
  const int g = b * NH_ + head;
  const u32* kg = key_t2 + ((size_t)g << 16) + dp;

  uint2 Wp[NP_];
  u32 I[NP_];
  #pragma unroll
  for (int p = 0; p < NP_; ++p) {
    size_t idx = (((size_t)g * NP_ + p) << 12) + hw;
    Wp[p] = wpk[idx];
    I[p]  = idx4[idx];
  }

  u32 v00[NP_], v01[NP_], v10[NP_], v11[NP_];
  #pragma unroll
  for (int p = 0; p < NP_; ++p) {
    u32 ip = I[p];
    int cx0 = ip & 63, cx1 = (ip >> 6) & 63, cy0 = (ip >> 12) & 63, cy1 = (ip >> 18) & 63;
    v00[p] = kg[((cy0 << 6) | cx0) * 16];
    v01[p] = kg[((cy0 << 6) | cx1) * 16];
    v10[p] = kg[((cy1 << 6) | cx0) * 16];
    v11[p] = kg[((cy1 << 6) | cx1) * 16];
  }

  float a0 = 0.f, a1 = 0.f;
  #pragma unroll
  for (int p = 0; p < NP_; ++p) {
    float2 w01 = __half22float2(*(const __half2*)&Wp[p].x);
    float2 w23 = __half22float2(*(const __half2*)&Wp[p].y);
    a0 = fmaf(w01.x, bflo(v00[p]), a0);
    a0 = fmaf(w01.y, bflo(v01[p]), a0);
    a0 = fmaf(w23.x, bflo(v10[p]), a0);
    a0 = fmaf(w23.y, bflo(v11[p]), a0);
    a1 = fmaf(w01.x, bfhi(v00[p]), a1);
    a1 = fmaf(w01.y, bfhi(v01[p]), a1);
    a1 = fmaf(w23.x, bfhi(v10[p]), a1);
    a1 = fmaf(w23.y, bfhi(v11[p]), a1);
  }
  feat2[((size_t)b * HW_ + hw) * 128 + c2] = (u32)f2bf(a0) | ((u32)f2bf(a1) << 16);
}

// ---------------------------------------------------------------------------
// Kernel 3: out = feat @ w_proj^T + b_proj via bf16 MFMA (validated, unchanged).
// ---------------------------------------------------------------------------
__global__ __launch_bounds__(256) void k_proj_mfma(const u16* __restrict__ A,
                                                   const u16* __restrict__ Bw,
                                                   const float* __restrict__ bias,
                                                   float* __restrict__ out) {
  __shared__ char smem[16384];
  const int t = threadIdx.x, w = t >> 6, l = t & 63;
  const int wm = w >> 1, wn = w & 1;
  const int bid = blockIdx.x;
  const int nb = bid & 1, mb = bid >> 1;
  const int r0 = mb * 128, n0 = nb * 128;

  f32x4 acc[4][4];
  #pragma unroll
  for (int m = 0; m < 4; ++m)
    #pragma unroll
    for (int n = 0; n < 4; ++n)
      acc[m][n] = (f32x4){0.f, 0.f, 0.f, 0.f};

  for (int k0 = 0; k0 < 256; k0 += 32) {
    if (w < 2) {
      #pragma unroll
      for (int j = 0; j < 4; ++j) {
        int i = w * 4 + j;
        int kq = i >> 1, half = i & 1;
        const u16* g = A + ((size_t)(r0 + half * 64 + l)) * 256 + k0 + kq * 8;
        __builtin_amdgcn_global_load_lds((const as1_u32*)g, (as3_u32*)(smem + i * 1024), 16, 0, 0);
      }
    } else {
      #pragma unroll
      for (int j = 0; j < 4; ++j) {
        int i = (w - 2) * 4 + j;
        int kq = i >> 1, half = i & 1;
        const u16* g = Bw + ((size_t)(n0 + half * 64 + l)) * 256 + k0 + kq * 8;
        __builtin_amdgcn_global_load_lds((const as1_u32*)g, (as3_u32*)(smem + 8192 + i * 1024), 16, 0, 0);
      }
    }
    __syncthreads();

    const int kq = l >> 4, lr = l & 15;
    bf16x8 af[4], bfr[4];
    #pragma unroll
    for (int m = 0; m < 4; ++m)
      af[m] = *(const bf16x8*)(smem + (kq * 128 + wm * 64 + m * 16 + lr) * 16);
    #pragma unroll
    for (int n = 0; n < 4; ++n)
      bfr[n] = *(const bf16x8*)(smem + 8192 + (kq * 128 + wn * 64 + n * 16 + lr) * 16);
    #pragma unroll
    for (int m = 0; m < 4; ++m)
      #pragma unroll
      for (int n = 0; n < 4; ++n)
        acc[m][n] = __builtin_amdgcn_mfma_f32_16x16x32_bf16(af[m], bfr[n], acc[m][n], 0, 0, 0);
    __syncthreads();
  }

  const int lr = l & 15, lq = l >> 4;
  #pragma unroll
  for (int n = 0; n < 4; ++n) {
    int col = n0 + wn * 64 + n * 16 + lr;
    float bv = bias[col];
    #pragma unroll
    for (int m = 0; m < 4; ++m) {
      int row = r0 + wm * 64 + m * 16 + lq * 4;
      #pragma unroll
      for (int r = 0; r < 4; ++r)
        out[(size_t)(row + r) * 256 + col] = acc[m][n][r] + bv;
    }
  }
}

// ---------------------------------------------------------------------------
extern "C" void kernel_launch(void* const* d_in, const int* in_sizes, int n_in,
                              void* d_out, int out_size, void* d_ws, size_t ws_size,
                              hipStream_t stream) {
  const float* query  = (const float*)d_in[0];
  const float* key    = (const float*)d_in[1];
  const float* w_off  = (const float*)d_in[2];
  const float* b_off  = (const float*)d_in[3];
  const float* w_proj = (const float*)d_in[4];
  const float* b_proj = (const float*)d_in[5];
  float* out = (float*)d_out;

  char* ws = (char*)d_ws;
  uint2*  wpk      = (uint2*)ws;                                //  8 MB
  u32*    idx4     = (u32*)(ws + (size_t)8  * 1024 * 1024);     //  4 MB
  u32*    key_t2   = (u32*)(ws + (size_t)16 * 1024 * 1024);     // 16 MB
  u32*    feat2    = (u32*)(ws + (size_t)32 * 1024 * 1024);     // 16 MB
  uint2*  wproj_bf = (uint2*)(ws + (size_t)48 * 1024 * 1024);   // 128 KB
  u32x4*  woff_sl  = (u32x4*)(ws + (size_t)49 * 1024 * 1024);   //  96 KB

  hipLaunchKernelGGL(k_trans_conv,   dim3(4184),  dim3(256), 0, stream,
                     key, w_proj, w_off, key_t2, wproj_bf, woff_sl);
  hipLaunchKernelGGL(k_offsets_mfma, dim3(512),   dim3(256), 0, stream,
                     query, (const u16*)woff_sl, b_off, wpk, idx4);
  hipLaunchKernelGGL(k_sample,       dim3(16384), dim3(256), 0, stream,
                     wpk, idx4, key_t2, feat2);
  hipLaunchKernelGGL(k_proj_mfma,    dim3(512),   dim3(256), 0, stream,
                     (const u16*)feat2, (const u16*)wproj_bf, b_proj, out);
}

// Round 13
// 62.940 us; speedup vs baseline: 1.2922x; 1.2922x over previous
//
#include <hip/hip_runtime.h>
#include <hip/hip_fp16.h>
#include <cstdint>

#define B_   8
#define C_   256
#define H_   64
#define W_   64
#define HW_  4096
#define NH_  8
#define NP_  4
#define DH_  32

typedef unsigned int u32;
typedef unsigned short u16;
typedef __attribute__((ext_vector_type(8))) short bf16x8;
typedef __attribute__((ext_vector_type(4))) float f32x4;
typedef __attribute__((ext_vector_type(4))) u32 u32x4;
typedef __attribute__((address_space(3))) u32 as3_u32;
typedef __attribute__((address_space(1))) u32 as1_u32;

__device__ __forceinline__ u16 f2bf(float f) {
  u32 u = __builtin_bit_cast(u32, f);
  return (u16)((u + 0x7FFFu + ((u >> 16) & 1u)) >> 16);
}
__device__ __forceinline__ float bflo(u32 v) { return __builtin_bit_cast(float, v << 16); }
__device__ __forceinline__ float bfhi(u32 v) { return __builtin_bit_cast(float, v & 0xFFFF0000u); }

// ---------------------------------------------------------------------------
// Kernel 1a: key transpose -> bf16 + w_proj convert (validated R11, unchanged).
// ---------------------------------------------------------------------------
__global__ __launch_bounds__(256) void k_trans_conv(const float* __restrict__ key,
                                                    const float* __restrict__ w_proj,
                                                    u32* __restrict__ key_t2,
                                                    uint2* __restrict__ wproj_bf) {
  __shared__ float tile[32 * 65];
  const int bid = blockIdx.x;
  const int t = threadIdx.x;

  if (bid < 4096) {
    const int g = bid >> 6;
    const int hw0 = (bid & 63) << 6;
    const float* kg = key + (size_t)g * DH_ * HW_ + hw0;
    #pragma unroll
    for (int k = 0; k < 8; ++k) {
      int idx = t + k * 256;
      int d = idx >> 6, j = idx & 63;
      tile[d * 65 + j] = kg[d * HW_ + j];
    }
    __syncthreads();
    u32* kt = key_t2 + ((size_t)g * HW_ + hw0) * 16;
    #pragma unroll
    for (int k = 0; k < 4; ++k) {
      int idx = t + k * 256;
      int j = idx >> 4, dp = idx & 15;
      u32 v = (u32)f2bf(tile[(2 * dp) * 65 + j]) | ((u32)f2bf(tile[(2 * dp + 1) * 65 + j]) << 16);
      kt[j * 16 + dp] = v;
    }
  } else {
    int i = (bid - 4096) * 256 + t;
    float4 v = ((const float4*)w_proj)[i];
    uint2 o;
    o.x = (u32)f2bf(v.x) | ((u32)f2bf(v.y) << 16);
    o.y = (u32)f2bf(v.z) | ((u32)f2bf(v.w) << 16);
    wproj_bf[i] = o;
  }
}

// ---------------------------------------------------------------------------
// Kernel 1b: offsets GEMM, R11 structure with 512-thread blocks (16 waves/CU).
// LDS: B 48KB [0,48K) + A 32KB [48K,80K) = 80KB -> 2 blocks/CU.
// Wave w: rows (w&3)*16.., cols (w>>2)*48.. (3 fragments).
// A-stage: 4 slots/thread, conflict-free ds_write_b128.
// Epilogue: softmax (1 task/thread) + f16 weights + packed idx, stride-97 LDS.
// ---------------------------------------------------------------------------
__global__ __launch_bounds__(512) void k_offsets_mfma(const float* __restrict__ query,
                                                      const float* __restrict__ w_off,
                                                      const float* __restrict__ b_off,
                                                      uint2* __restrict__ wpk,
                                                      u32* __restrict__ idx4) {
  __shared__ char smem[81920];
  const int t = threadIdx.x, l = t & 63, w = t >> 6;
  const int lr = l & 15, lq = l >> 4;
  const int wr = w & 3, wc = w >> 2;
  const int r0 = blockIdx.x * 64;
  const int b  = r0 >> 12;
  const int hw0 = r0 & 4095;

  // ---- B stage: w_off (96x256 f32) -> bf16 swizzled slots ----
  {
    const float4* w4 = (const float4*)w_off;
    #pragma unroll
    for (int j = 0; j < 6; ++j) {
      int m = t + j * 512;               // col*32 + chunk, 0..3071
      int col = m >> 5, ch = m & 31;
      float4 lo = w4[m * 2];
      float4 hi = w4[m * 2 + 1];
      u32x4 v;
      v.x = (u32)f2bf(lo.x) | ((u32)f2bf(lo.y) << 16);
      v.y = (u32)f2bf(lo.z) | ((u32)f2bf(lo.w) << 16);
      v.z = (u32)f2bf(hi.x) | ((u32)f2bf(hi.y) << 16);
      v.w = (u32)f2bf(hi.z) | ((u32)f2bf(hi.w) << 16);
      int slot = (col << 5) | (ch ^ (col & 7));
      *(u32x4*)(smem + slot * 16) = v;
    }
  }

  // ---- A stage: 2048 slots (kc 0..31 x row 0..63), 4 slots/thread ----
  {
    const float* qb = query + ((size_t)b * 256) * 4096 + hw0;
    #pragma unroll
    for (int s = 0; s < 4; ++s) {
      int sid = t + s * 512;             // kc*64 + i ; wave-uniform kc, i=lane
      int kc = sid >> 6, i = sid & 63;
      const float* src = qb + (size_t)(kc * 8) * 4096 + i;
      u32x4 v;
      #pragma unroll
      for (int m = 0; m < 4; ++m) {
        float c0 = src[(size_t)(2 * m) * 4096];
        float c1 = src[(size_t)(2 * m + 1) * 4096];
        ((u32*)&v)[m] = (u32)f2bf(c0) | ((u32)f2bf(c1) << 16);
      }
      *(u32x4*)(smem + 49152 + sid * 16) = v;   // ds_write_b128, conflict-free
    }
  }
  __syncthreads();

  // ---- MFMA: wave = rows wr*16.., cols wc*48..; 3 fragments ----
  f32x4 acc[3];
  #pragma unroll
  for (int n = 0; n < 3; ++n) acc[n] = (f32x4){0.f, 0.f, 0.f, 0.f};

  #pragma unroll
  for (int step = 0; step < 8; ++step) {
    const int kc = step * 4 + lq;
    bf16x8 af = *(const bf16x8*)(smem + 49152 + (kc * 64 + wr * 16 + lr) * 16);
    #pragma unroll
    for (int n = 0; n < 3; ++n) {
      int col = wc * 48 + n * 16 + lr;
      bf16x8 bfr = *(const bf16x8*)(smem + ((col << 5) | (kc ^ (col & 7))) * 16);
      acc[n] = __builtin_amdgcn_mfma_f32_16x16x32_bf16(af, bfr, acc[n], 0, 0, 0);
    }
  }
  __syncthreads();

  // ---- epilogue: acc -> LDS [row][o] stride 97 (conflict-free), + bias ----
  float* epi = (float*)smem;
  #pragma unroll
  for (int n = 0; n < 3; ++n) {
    int o = wc * 48 + n * 16 + lr;
    float bo = b_off[o];
    int row = wr * 16 + lq * 4;
    #pragma unroll
    for (int r = 0; r < 4; ++r)
      epi[(row + r) * 97 + o] = acc[n][r] + bo;
  }
  __syncthreads();

  // ---- softmax + f16-packed weights/indices: 1 task/thread (64 rows x 8 heads) ----
  {
    int row = t & 63, head = t >> 6;
    const float* o = epi + row * 97 + head * 12;
    float ox[NP_], oy[NP_], lg[NP_];
    #pragma unroll
    for (int p = 0; p < NP_; ++p) {
      ox[p] = o[p * 3 + 0];
      oy[p] = o[p * 3 + 1];
      lg[p] = o[p * 3 + 2];
    }
    float mx = fmaxf(fmaxf(lg[0], lg[1]), fmaxf(lg[2], lg[3]));
    float e[NP_];
    float s = 0.f;
    #pragma unroll
    for (int p = 0; p < NP_; ++p) { e[p] = expf(lg[p] - mx); s += e[p]; }
    float inv = 1.f / s;

    int hw = hw0 + row;
    float wq = (float)(hw & 63);
    float hq = (float)(hw >> 6);
    size_t base = ((size_t)(b * NH_ + head) * HW_ + hw) * NP_;
    #pragma unroll
    for (int p = 0; p < NP_; ++p) {
      float wt = e[p] * inv;
      float x = wq + ox[p] * 3.15f;
      float y = hq + oy[p] * 3.15f;
      float x0f = floorf(x), y0f = floorf(y);
      int ix0 = (int)x0f, iy0 = (int)y0f;
      int ix1 = ix0 + 1, iy1 = iy0 + 1;
      float fx = x - x0f, fy = y - y0f;
      float gx0 = 1.f - fx, gy0 = 1.f - fy;

      bool vx0 = (ix0 >= 0) & (ix0 <= W_ - 1);
      bool vx1 = (ix1 >= 0) & (ix1 <= W_ - 1);
      bool vy0 = (iy0 >= 0) & (iy0 <= H_ - 1);
      bool vy1 = (iy1 >= 0) & (iy1 <= H_ - 1);
      int cx0 = min(max(ix0, 0), W_ - 1), cx1 = min(max(ix1, 0), W_ - 1);
      int cy0 = min(max(iy0, 0), H_ - 1), cy1 = min(max(iy1, 0), H_ - 1);

      float w00 = wt * gx0 * gy0 * ((vx0 & vy0) ? 1.f : 0.f);
      float w01 = wt * fx  * gy0 * ((vx1 & vy0) ? 1.f : 0.f);
      float w10 = wt * gx0 * fy  * ((vx0 & vy1) ? 1.f : 0.f);
      float w11 = wt * fx  * fy  * ((vx1 & vy1) ? 1.f : 0.f);

      __half2 h01 = __floats2half2_rn(w00, w01);
      __half2 h23 = __floats2half2_rn(w10, w11);
      uint2 pk;
      pk.x = *(u32*)&h01;
      pk.y = *(u32*)&h23;
      wpk[base + p]  = pk;
      idx4[base + p] = (u32)cx0 | ((u32)cx1 << 6) | ((u32)cy0 << 12) | ((u32)cy1 << 18);
    }
  }
}

// ---------------------------------------------------------------------------
// Kernel 2: bilinear gather + weighted sum (f16 weights, [g][hw][p] params).
// (validated R11, unchanged)
// ---------------------------------------------------------------------------
__global__ __launch_bounds__(256) void k_sample(const uint2* __restrict__ wpk,
                                                const u32* __restrict__ idx4,
                                                const u32* __restrict__ key_t2,
                                                u32* __restrict__ feat2) {
  const int t = threadIdx.x;
  const int hwid = blockIdx.x * 2 + (t >> 7);
  const int b = hwid >> 12;
  const int hw = hwid & 4095;
  const int c2 = t & 127;
  const int head = c2 >> 4, dp = c2 & 15;
  const int g = b * NH_ + head;
  const size_t pbase = (((size_t)g << 12) + hw) * NP_;
  const u32* kg = key_t2 + ((size_t)g << 16) + dp;

  uint2 Wp[NP_];
  u32 I[NP_];
  #pragma unroll
  for (int p = 0; p < NP_; ++p) { Wp[p] = wpk[pbase + p]; I[p] = idx4[pbase + p]; }

  u32 v00[NP_], v01[NP_], v10[NP_], v11[NP_];
  #pragma unroll
  for (int p = 0; p < NP_; ++p) {
    u32 ip = I[p];
    int cx0 = ip & 63, cx1 = (ip >> 6) & 63, cy0 = (ip >> 12) & 63, cy1 = (ip >> 18) & 63;
    v00[p] = kg[((cy0 << 6) | cx0) * 16];
    v01[p] = kg[((cy0 << 6) | cx1) * 16];
    v10[p] = kg[((cy1 << 6) | cx0) * 16];
    v11[p] = kg[((cy1 << 6) | cx1) * 16];
  }

  float a0 = 0.f, a1 = 0.f;
  #pragma unroll
  for (int p = 0; p < NP_; ++p) {
    float2 w01 = __half22float2(*(const __half2*)&Wp[p].x);
    float2 w23 = __half22float2(*(const __half2*)&Wp[p].y);
    a0 = fmaf(w01.x, bflo(v00[p]), a0);
    a0 = fmaf(w01.y, bflo(v01[p]), a0);
    a0 = fmaf(w23.x, bflo(v10[p]), a0);
    a0 = fmaf(w23.y, bflo(v11[p]), a0);
    a1 = fmaf(w01.x, bfhi(v00[p]), a1);
    a1 = fmaf(w01.y, bfhi(v01[p]), a1);
    a1 = fmaf(w23.x, bfhi(v10[p]), a1);
    a1 = fmaf(w23.y, bfhi(v11[p]), a1);
  }
  feat2[((size_t)b * HW_ + hw) * 128 + c2] = (u32)f2bf(a0) | ((u32)f2bf(a1) << 16);
}

// ---------------------------------------------------------------------------
// Kernel 3: out = feat @ w_proj^T + b_proj via bf16 MFMA (validated, unchanged).
// ---------------------------------------------------------------------------
__global__ __launch_bounds__(256) void k_proj_mfma(const u16* __restrict__ A,
                                                   const u16* __restrict__ Bw,
                                                   const float* __restrict__ bias,
                                                   float* __restrict__ out) {
  __shared__ char smem[16384];
  const int t = threadIdx.x, w = t >> 6, l = t & 63;
  const int wm = w >> 1, wn = w & 1;
  const int bid = blockIdx.x;
  const int nb = bid & 1, mb = bid >> 1;
  const int r0 = mb * 128, n0 = nb * 128;

  f32x4 acc[4][4];
  #pragma unroll
  for (int m = 0; m < 4; ++m)
    #pragma unroll
    for (int n = 0; n < 4; ++n)
      acc[m][n] = (f32x4){0.f, 0.f, 0.f, 0.f};

  for (int k0 = 0; k0 < 256; k0 += 32) {
    if (w < 2) {
      #pragma unroll
      for (int j = 0; j < 4; ++j) {
        int i = w * 4 + j;
        int kq = i >> 1, half = i & 1;
        const u16* g = A + ((size_t)(r0 + half * 64 + l)) * 256 + k0 + kq * 8;
        __builtin_amdgcn_global_load_lds((const as1_u32*)g, (as3_u32*)(smem + i * 1024), 16, 0, 0);
      }
    } else {
      #pragma unroll
      for (int j = 0; j < 4; ++j) {
        int i = (w - 2) * 4 + j;
        int kq = i >> 1, half = i & 1;
        const u16* g = Bw + ((size_t)(n0 + half * 64 + l)) * 256 + k0 + kq * 8;
        __builtin_amdgcn_global_load_lds((const as1_u32*)g, (as3_u32*)(smem + 8192 + i * 1024), 16, 0, 0);
      }
    }
    __syncthreads();

    const int kq = l >> 4, lr = l & 15;
    bf16x8 af[4], bfr[4];
    #pragma unroll
    for (int m = 0; m < 4; ++m)
      af[m] = *(const bf16x8*)(smem + (kq * 128 + wm * 64 + m * 16 + lr) * 16);
    #pragma unroll
    for (int n = 0; n < 4; ++n)
      bfr[n] = *(const bf16x8*)(smem + 8192 + (kq * 128 + wn * 64 + n * 16 + lr) * 16);
    #pragma unroll
    for (int m = 0; m < 4; ++m)
      #pragma unroll
      for (int n = 0; n < 4; ++n)
        acc[m][n] = __builtin_amdgcn_mfma_f32_16x16x32_bf16(af[m], bfr[n], acc[m][n], 0, 0, 0);
    __syncthreads();
  }

  const int lr = l & 15, lq = l >> 4;
  #pragma unroll
  for (int n = 0; n < 4; ++n) {
    int col = n0 + wn * 64 + n * 16 + lr;
    float bv = bias[col];
    #pragma unroll
    for (int m = 0; m < 4; ++m) {
      int row = r0 + wm * 64 + m * 16 + lq * 4;
      #pragma unroll
      for (int r = 0; r < 4; ++r)
        out[(size_t)(row + r) * 256 + col] = acc[m][n][r] + bv;
    }
  }
}

// ---------------------------------------------------------------------------
extern "C" void kernel_launch(void* const* d_in, const int* in_sizes, int n_in,
                              void* d_out, int out_size, void* d_ws, size_t ws_size,
                              hipStream_t stream) {
  const float* query  = (const float*)d_in[0];
  const float* key    = (const float*)d_in[1];
  const float* w_off  = (const float*)d_in[2];
  const float* b_off  = (const float*)d_in[3];
  const float* w_proj = (const float*)d_in[4];
  const float* b_proj = (const float*)d_in[5];
  float* out = (float*)d_out;

  char* ws = (char*)d_ws;
  uint2*  wpk      = (uint2*)ws;                                //  8 MB
  u32*    idx4     = (u32*)(ws + (size_t)8  * 1024 * 1024);     //  4 MB
  u32*    key_t2   = (u32*)(ws + (size_t)16 * 1024 * 1024);     // 16 MB
  u32*    feat2    = (u32*)(ws + (size_t)32 * 1024 * 1024);     // 16 MB
  uint2*  wproj_bf = (uint2*)(ws + (size_t)48 * 1024 * 1024);   // 128 KB

  hipLaunchKernelGGL(k_trans_conv,   dim3(4160),  dim3(256), 0, stream,
                     key, w_proj, key_t2, wproj_bf);
  hipLaunchKernelGGL(k_offsets_mfma, dim3(512),   dim3(512), 0, stream,
                     query, w_off, b_off, wpk, idx4);
  hipLaunchKernelGGL(k_sample,       dim3(16384), dim3(256), 0, stream,
                     wpk, idx4, key_t2, feat2);
  hipLaunchKernelGGL(k_proj_mfma,    dim3(512),   dim3(256), 0, stream,
                     (const u16*)feat2, (const u16*)wproj_bf, b_proj, out);
}

// Round 14
// 62.514 us; speedup vs baseline: 1.3011x; 1.0068x over previous
//
#include <hip/hip_runtime.h>
#include <hip/hip_fp16.h>
#include <cstdint>

#define B_   8
#define C_   256
#define H_   64
#define W_   64
#define HW_  4096
#define NH_  8
#define NP_  4
#define DH_  32

typedef unsigned int u32;
typedef unsigned short u16;
typedef __attribute__((ext_vector_type(8))) short bf16x8;
typedef __attribute__((ext_vector_type(4))) float f32x4;
typedef __attribute__((ext_vector_type(4))) u32 u32x4;
typedef __attribute__((address_space(3))) u32 as3_u32;
typedef __attribute__((address_space(1))) u32 as1_u32;

__device__ __forceinline__ u16 f2bf(float f) {
  u32 u = __builtin_bit_cast(u32, f);
  return (u16)((u + 0x7FFFu + ((u >> 16) & 1u)) >> 16);
}
__device__ __forceinline__ float bflo(u32 v) { return __builtin_bit_cast(float, v << 16); }
__device__ __forceinline__ float bfhi(u32 v) { return __builtin_bit_cast(float, v & 0xFFFF0000u); }

// ---------------------------------------------------------------------------
// Kernel 1a: key transpose -> bf16 + w_proj convert (validated, unchanged).
// ---------------------------------------------------------------------------
__global__ __launch_bounds__(256) void k_trans_conv(const float* __restrict__ key,
                                                    const float* __restrict__ w_proj,
                                                    u32* __restrict__ key_t2,
                                                    uint2* __restrict__ wproj_bf) {
  __shared__ float tile[32 * 65];
  const int bid = blockIdx.x;
  const int t = threadIdx.x;

  if (bid < 4096) {
    const int g = bid >> 6;
    const int hw0 = (bid & 63) << 6;
    const float* kg = key + (size_t)g * DH_ * HW_ + hw0;
    #pragma unroll
    for (int k = 0; k < 8; ++k) {
      int idx = t + k * 256;
      int d = idx >> 6, j = idx & 63;
      tile[d * 65 + j] = kg[d * HW_ + j];
    }
    __syncthreads();
    u32* kt = key_t2 + ((size_t)g * HW_ + hw0) * 16;
    #pragma unroll
    for (int k = 0; k < 4; ++k) {
      int idx = t + k * 256;
      int j = idx >> 4, dp = idx & 15;
      u32 v = (u32)f2bf(tile[(2 * dp) * 65 + j]) | ((u32)f2bf(tile[(2 * dp + 1) * 65 + j]) << 16);
      kt[j * 16 + dp] = v;
    }
  } else {
    int i = (bid - 4096) * 256 + t;
    float4 v = ((const float4*)w_proj)[i];
    uint2 o;
    o.x = (u32)f2bf(v.x) | ((u32)f2bf(v.y) << 16);
    o.y = (u32)f2bf(v.z) | ((u32)f2bf(v.w) << 16);
    wproj_bf[i] = o;
  }
}

// ---------------------------------------------------------------------------
// Kernel 1b: offsets GEMM, 512-thread blocks (validated R13, unchanged).
// ---------------------------------------------------------------------------
__global__ __launch_bounds__(512) void k_offsets_mfma(const float* __restrict__ query,
                                                      const float* __restrict__ w_off,
                                                      const float* __restrict__ b_off,
                                                      uint2* __restrict__ wpk,
                                                      u32* __restrict__ idx4) {
  __shared__ char smem[81920];
  const int t = threadIdx.x, l = t & 63, w = t >> 6;
  const int lr = l & 15, lq = l >> 4;
  const int wr = w & 3, wc = w >> 2;
  const int r0 = blockIdx.x * 64;
  const int b  = r0 >> 12;
  const int hw0 = r0 & 4095;

  {
    const float4* w4 = (const float4*)w_off;
    #pragma unroll
    for (int j = 0; j < 6; ++j) {
      int m = t + j * 512;
      int col = m >> 5, ch = m & 31;
      float4 lo = w4[m * 2];
      float4 hi = w4[m * 2 + 1];
      u32x4 v;
      v.x = (u32)f2bf(lo.x) | ((u32)f2bf(lo.y) << 16);
      v.y = (u32)f2bf(lo.z) | ((u32)f2bf(lo.w) << 16);
      v.z = (u32)f2bf(hi.x) | ((u32)f2bf(hi.y) << 16);
      v.w = (u32)f2bf(hi.z) | ((u32)f2bf(hi.w) << 16);
      int slot = (col << 5) | (ch ^ (col & 7));
      *(u32x4*)(smem + slot * 16) = v;
    }
  }

  {
    const float* qb = query + ((size_t)b * 256) * 4096 + hw0;
    #pragma unroll
    for (int s = 0; s < 4; ++s) {
      int sid = t + s * 512;
      int kc = sid >> 6, i = sid & 63;
      const float* src = qb + (size_t)(kc * 8) * 4096 + i;
      u32x4 v;
      #pragma unroll
      for (int m = 0; m < 4; ++m) {
        float c0 = src[(size_t)(2 * m) * 4096];
        float c1 = src[(size_t)(2 * m + 1) * 4096];
        ((u32*)&v)[m] = (u32)f2bf(c0) | ((u32)f2bf(c1) << 16);
      }
      *(u32x4*)(smem + 49152 + sid * 16) = v;
    }
  }
  __syncthreads();

  f32x4 acc[3];
  #pragma unroll
  for (int n = 0; n < 3; ++n) acc[n] = (f32x4){0.f, 0.f, 0.f, 0.f};

  #pragma unroll
  for (int step = 0; step < 8; ++step) {
    const int kc = step * 4 + lq;
    bf16x8 af = *(const bf16x8*)(smem + 49152 + (kc * 64 + wr * 16 + lr) * 16);
    #pragma unroll
    for (int n = 0; n < 3; ++n) {
      int col = wc * 48 + n * 16 + lr;
      bf16x8 bfr = *(const bf16x8*)(smem + ((col << 5) | (kc ^ (col & 7))) * 16);
      acc[n] = __builtin_amdgcn_mfma_f32_16x16x32_bf16(af, bfr, acc[n], 0, 0, 0);
    }
  }
  __syncthreads();

  float* epi = (float*)smem;
  #pragma unroll
  for (int n = 0; n < 3; ++n) {
    int o = wc * 48 + n * 16 + lr;
    float bo = b_off[o];
    int row = wr * 16 + lq * 4;
    #pragma unroll
    for (int r = 0; r < 4; ++r)
      epi[(row + r) * 97 + o] = acc[n][r] + bo;
  }
  __syncthreads();

  {
    int row = t & 63, head = t >> 6;
    const float* o = epi + row * 97 + head * 12;
    float ox[NP_], oy[NP_], lg[NP_];
    #pragma unroll
    for (int p = 0; p < NP_; ++p) {
      ox[p] = o[p * 3 + 0];
      oy[p] = o[p * 3 + 1];
      lg[p] = o[p * 3 + 2];
    }
    float mx = fmaxf(fmaxf(lg[0], lg[1]), fmaxf(lg[2], lg[3]));
    float e[NP_];
    float s = 0.f;
    #pragma unroll
    for (int p = 0; p < NP_; ++p) { e[p] = expf(lg[p] - mx); s += e[p]; }
    float inv = 1.f / s;

    int hw = hw0 + row;
    float wq = (float)(hw & 63);
    float hq = (float)(hw >> 6);
    size_t base = ((size_t)(b * NH_ + head) * HW_ + hw) * NP_;
    #pragma unroll
    for (int p = 0; p < NP_; ++p) {
      float wt = e[p] * inv;
      float x = wq + ox[p] * 3.15f;
      float y = hq + oy[p] * 3.15f;
      float x0f = floorf(x), y0f = floorf(y);
      int ix0 = (int)x0f, iy0 = (int)y0f;
      int ix1 = ix0 + 1, iy1 = iy0 + 1;
      float fx = x - x0f, fy = y - y0f;
      float gx0 = 1.f - fx, gy0 = 1.f - fy;

      bool vx0 = (ix0 >= 0) & (ix0 <= W_ - 1);
      bool vx1 = (ix1 >= 0) & (ix1 <= W_ - 1);
      bool vy0 = (iy0 >= 0) & (iy0 <= H_ - 1);
      bool vy1 = (iy1 >= 0) & (iy1 <= H_ - 1);
      int cx0 = min(max(ix0, 0), W_ - 1), cx1 = min(max(ix1, 0), W_ - 1);
      int cy0 = min(max(iy0, 0), H_ - 1), cy1 = min(max(iy1, 0), H_ - 1);

      float w00 = wt * gx0 * gy0 * ((vx0 & vy0) ? 1.f : 0.f);
      float w01 = wt * fx  * gy0 * ((vx1 & vy0) ? 1.f : 0.f);
      float w10 = wt * gx0 * fy  * ((vx0 & vy1) ? 1.f : 0.f);
      float w11 = wt * fx  * fy  * ((vx1 & vy1) ? 1.f : 0.f);

      __half2 h01 = __floats2half2_rn(w00, w01);
      __half2 h23 = __floats2half2_rn(w10, w11);
      uint2 pk;
      pk.x = *(u32*)&h01;
      pk.y = *(u32*)&h23;
      wpk[base + p]  = pk;
      idx4[base + p] = (u32)cx0 | ((u32)cx1 << 6) | ((u32)cy0 << 12) | ((u32)cy1 << 18);
    }
  }
}

// ---------------------------------------------------------------------------
// Kernel 2: bilinear gather + weighted sum (validated, unchanged).
// ---------------------------------------------------------------------------
__global__ __launch_bounds__(256) void k_sample(const uint2* __restrict__ wpk,
                                                const u32* __restrict__ idx4,
                                                const u32* __restrict__ key_t2,
                                                u32* __restrict__ feat2) {
  const int t = threadIdx.x;
  const int hwid = blockIdx.x * 2 + (t >> 7);
  const int b = hwid >> 12;
  const int hw = hwid & 4095;
  const int c2 = t & 127;
  const int head = c2 >> 4, dp = c2 & 15;
  const int g = b * NH_ + head;
  const size_t pbase = (((size_t)g << 12) + hw) * NP_;
  const u32* kg = key_t2 + ((size_t)g << 16) + dp;

  uint2 Wp[NP_];
  u32 I[NP_];
  #pragma unroll
  for (int p = 0; p < NP_; ++p) { Wp[p] = wpk[pbase + p]; I[p] = idx4[pbase + p]; }

  u32 v00[NP_], v01[NP_], v10[NP_], v11[NP_];
  #pragma unroll
  for (int p = 0; p < NP_; ++p) {
    u32 ip = I[p];
    int cx0 = ip & 63, cx1 = (ip >> 6) & 63, cy0 = (ip >> 12) & 63, cy1 = (ip >> 18) & 63;
    v00[p] = kg[((cy0 << 6) | cx0) * 16];
    v01[p] = kg[((cy0 << 6) | cx1) * 16];
    v10[p] = kg[((cy1 << 6) | cx0) * 16];
    v11[p] = kg[((cy1 << 6) | cx1) * 16];
  }

  float a0 = 0.f, a1 = 0.f;
  #pragma unroll
  for (int p = 0; p < NP_; ++p) {
    float2 w01 = __half22float2(*(const __half2*)&Wp[p].x);
    float2 w23 = __half22float2(*(const __half2*)&Wp[p].y);
    a0 = fmaf(w01.x, bflo(v00[p]), a0);
    a0 = fmaf(w01.y, bflo(v01[p]), a0);
    a0 = fmaf(w23.x, bflo(v10[p]), a0);
    a0 = fmaf(w23.y, bflo(v11[p]), a0);
    a1 = fmaf(w01.x, bfhi(v00[p]), a1);
    a1 = fmaf(w01.y, bfhi(v01[p]), a1);
    a1 = fmaf(w23.x, bfhi(v10[p]), a1);
    a1 = fmaf(w23.y, bfhi(v11[p]), a1);
  }
  feat2[((size_t)b * HW_ + hw) * 128 + c2] = (u32)f2bf(a0) | ((u32)f2bf(a1) << 16);
}

// ---------------------------------------------------------------------------
// Kernel 3: out = feat @ w_proj^T + b_proj. Full-width blocks: M=64, N=256,
// grid 512 -> A read ONCE (16MB). LDS 20KB: A chunk [kq 0..3][row 0..63] 4KB,
// B chunk [kq 0..3][col 0..255] 16KB. Wave w = rows w*16..; 16 col-fragments.
// (GEMM phase layout validated in R4-fused kernel.)
// ---------------------------------------------------------------------------
__global__ __launch_bounds__(256) void k_proj_mfma(const u16* __restrict__ A,
                                                   const u16* __restrict__ Bw,
                                                   const float* __restrict__ bias,
                                                   float* __restrict__ out) {
  __shared__ char smem[20480];  // A: [0,4K)  B: [4K,20K)
  const int t = threadIdx.x, l = t & 63, w = t >> 6;
  const int lr = l & 15, lq = l >> 4;
  const int r0 = blockIdx.x * 64;

  f32x4 acc[16];
  #pragma unroll
  for (int n = 0; n < 16; ++n) acc[n] = (f32x4){0.f, 0.f, 0.f, 0.f};

  for (int k0 = 0; k0 < 256; k0 += 32) {
    // A stage: 4 issues (one per wave): kq=w, rows=lanes
    {
      const u16* g = A + ((size_t)(r0 + l)) * 256 + k0 + w * 8;
      __builtin_amdgcn_global_load_lds((const as1_u32*)g,
          (as3_u32*)(smem + w * 1024), 16, 0, 0);
    }
    // B stage: 16 issues, 4 per wave: slots [kq][cg*64+l]
    #pragma unroll
    for (int j = 0; j < 4; ++j) {
      int i = w * 4 + j;
      int kq = i >> 2, cg = i & 3;
      const u16* g = Bw + ((size_t)(cg * 64 + l)) * 256 + k0 + kq * 8;
      __builtin_amdgcn_global_load_lds((const as1_u32*)g,
          (as3_u32*)(smem + 4096 + (kq * 256 + cg * 64) * 16), 16, 0, 0);
    }
    __syncthreads();

    bf16x8 af = *(const bf16x8*)(smem + (lq * 64 + w * 16 + lr) * 16);
    #pragma unroll
    for (int n = 0; n < 16; ++n) {
      bf16x8 bfr = *(const bf16x8*)(smem + 4096 + (lq * 256 + n * 16 + lr) * 16);
      acc[n] = __builtin_amdgcn_mfma_f32_16x16x32_bf16(af, bfr, acc[n], 0, 0, 0);
    }
    __syncthreads();
  }

  #pragma unroll
  for (int n = 0; n < 16; ++n) {
    int col = n * 16 + lr;
    float bv = bias[col];
    int row = r0 + w * 16 + lq * 4;
    #pragma unroll
    for (int r = 0; r < 4; ++r)
      out[(size_t)(row + r) * 256 + col] = acc[n][r] + bv;
  }
}

// ---------------------------------------------------------------------------
extern "C" void kernel_launch(void* const* d_in, const int* in_sizes, int n_in,
                              void* d_out, int out_size, void* d_ws, size_t ws_size,
                              hipStream_t stream) {
  const float* query  = (const float*)d_in[0];
  const float* key    = (const float*)d_in[1];
  const float* w_off  = (const float*)d_in[2];
  const float* b_off  = (const float*)d_in[3];
  const float* w_proj = (const float*)d_in[4];
  const float* b_proj = (const float*)d_in[5];
  float* out = (float*)d_out;

  char* ws = (char*)d_ws;
  uint2*  wpk      = (uint2*)ws;                                //  8 MB
  u32*    idx4     = (u32*)(ws + (size_t)8  * 1024 * 1024);     //  4 MB
  u32*    key_t2   = (u32*)(ws + (size_t)16 * 1024 * 1024);     // 16 MB
  u32*    feat2    = (u32*)(ws + (size_t)32 * 1024 * 1024);     // 16 MB
  uint2*  wproj_bf = (uint2*)(ws + (size_t)48 * 1024 * 1024);   // 128 KB

  hipLaunchKernelGGL(k_trans_conv,   dim3(4160),  dim3(256), 0, stream,
                     key, w_proj, key_t2, wproj_bf);
  hipLaunchKernelGGL(k_offsets_mfma, dim3(512),   dim3(512), 0, stream,
                     query, w_off, b_off, wpk, idx4);
  hipLaunchKernelGGL(k_sample,       dim3(16384), dim3(256), 0, stream,
                     wpk, idx4, key_t2, feat2);
  hipLaunchKernelGGL(k_proj_mfma,    dim3(512),   dim3(256), 0, stream,
                     (const u16*)feat2, (const u16*)wproj_bf, b_proj, out);
}

// Round 15
// 61.785 us; speedup vs baseline: 1.3164x; 1.0118x over previous
//
#include <hip/hip_runtime.h>
#include <hip/hip_fp16.h>
#include <cstdint>

#define B_   8
#define C_   256
#define H_   64
#define W_   64
#define HW_  4096
#define NH_  8
#define NP_  4
#define DH_  32

typedef unsigned int u32;
typedef unsigned short u16;
typedef __attribute__((ext_vector_type(8))) short bf16x8;
typedef __attribute__((ext_vector_type(4))) float f32x4;
typedef __attribute__((ext_vector_type(4))) u32 u32x4;
typedef __attribute__((address_space(3))) u32 as3_u32;
typedef __attribute__((address_space(1))) u32 as1_u32;

__device__ __forceinline__ u16 f2bf(float f) {
  u32 u = __builtin_bit_cast(u32, f);
  return (u16)((u + 0x7FFFu + ((u >> 16) & 1u)) >> 16);
}
__device__ __forceinline__ float bflo(u32 v) { return __builtin_bit_cast(float, v << 16); }
__device__ __forceinline__ float bfhi(u32 v) { return __builtin_bit_cast(float, v & 0xFFFF0000u); }

// ---------------------------------------------------------------------------
// Kernel 1a: key transpose -> bf16 + w_proj convert (validated, unchanged).
// ---------------------------------------------------------------------------
__global__ __launch_bounds__(256) void k_trans_conv(const float* __restrict__ key,
                                                    const float* __restrict__ w_proj,
                                                    u32* __restrict__ key_t2,
                                                    uint2* __restrict__ wproj_bf) {
  __shared__ float tile[32 * 65];
  const int bid = blockIdx.x;
  const int t = threadIdx.x;

  if (bid < 4096) {
    const int g = bid >> 6;
    const int hw0 = (bid & 63) << 6;
    const float* kg = key + (size_t)g * DH_ * HW_ + hw0;
    #pragma unroll
    for (int k = 0; k < 8; ++k) {
      int idx = t + k * 256;
      int d = idx >> 6, j = idx & 63;
      tile[d * 65 + j] = kg[d * HW_ + j];
    }
    __syncthreads();
    u32* kt = key_t2 + ((size_t)g * HW_ + hw0) * 16;
    #pragma unroll
    for (int k = 0; k < 4; ++k) {
      int idx = t + k * 256;
      int j = idx >> 4, dp = idx & 15;
      u32 v = (u32)f2bf(tile[(2 * dp) * 65 + j]) | ((u32)f2bf(tile[(2 * dp + 1) * 65 + j]) << 16);
      kt[j * 16 + dp] = v;
    }
  } else {
    int i = (bid - 4096) * 256 + t;
    float4 v = ((const float4*)w_proj)[i];
    uint2 o;
    o.x = (u32)f2bf(v.x) | ((u32)f2bf(v.y) << 16);
    o.y = (u32)f2bf(v.z) | ((u32)f2bf(v.w) << 16);
    wproj_bf[i] = o;
  }
}

// ---------------------------------------------------------------------------
// Kernel 1b: offsets GEMM, 512-thread blocks (validated R13, unchanged).
// ---------------------------------------------------------------------------
__global__ __launch_bounds__(512) void k_offsets_mfma(const float* __restrict__ query,
                                                      const float* __restrict__ w_off,
                                                      const float* __restrict__ b_off,
                                                      uint2* __restrict__ wpk,
                                                      u32* __restrict__ idx4) {
  __shared__ char smem[81920];
  const int t = threadIdx.x, l = t & 63, w = t >> 6;
  const int lr = l & 15, lq = l >> 4;
  const int wr = w & 3, wc = w >> 2;
  const int r0 = blockIdx.x * 64;
  const int b  = r0 >> 12;
  const int hw0 = r0 & 4095;

  {
    const float4* w4 = (const float4*)w_off;
    #pragma unroll
    for (int j = 0; j < 6; ++j) {
      int m = t + j * 512;
      int col = m >> 5, ch = m & 31;
      float4 lo = w4[m * 2];
      float4 hi = w4[m * 2 + 1];
      u32x4 v;
      v.x = (u32)f2bf(lo.x) | ((u32)f2bf(lo.y) << 16);
      v.y = (u32)f2bf(lo.z) | ((u32)f2bf(lo.w) << 16);
      v.z = (u32)f2bf(hi.x) | ((u32)f2bf(hi.y) << 16);
      v.w = (u32)f2bf(hi.z) | ((u32)f2bf(hi.w) << 16);
      int slot = (col << 5) | (ch ^ (col & 7));
      *(u32x4*)(smem + slot * 16) = v;
    }
  }

  {
    const float* qb = query + ((size_t)b * 256) * 4096 + hw0;
    #pragma unroll
    for (int s = 0; s < 4; ++s) {
      int sid = t + s * 512;
      int kc = sid >> 6, i = sid & 63;
      const float* src = qb + (size_t)(kc * 8) * 4096 + i;
      u32x4 v;
      #pragma unroll
      for (int m = 0; m < 4; ++m) {
        float c0 = src[(size_t)(2 * m) * 4096];
        float c1 = src[(size_t)(2 * m + 1) * 4096];
        ((u32*)&v)[m] = (u32)f2bf(c0) | ((u32)f2bf(c1) << 16);
      }
      *(u32x4*)(smem + 49152 + sid * 16) = v;
    }
  }
  __syncthreads();

  f32x4 acc[3];
  #pragma unroll
  for (int n = 0; n < 3; ++n) acc[n] = (f32x4){0.f, 0.f, 0.f, 0.f};

  #pragma unroll
  for (int step = 0; step < 8; ++step) {
    const int kc = step * 4 + lq;
    bf16x8 af = *(const bf16x8*)(smem + 49152 + (kc * 64 + wr * 16 + lr) * 16);
    #pragma unroll
    for (int n = 0; n < 3; ++n) {
      int col = wc * 48 + n * 16 + lr;
      bf16x8 bfr = *(const bf16x8*)(smem + ((col << 5) | (kc ^ (col & 7))) * 16);
      acc[n] = __builtin_amdgcn_mfma_f32_16x16x32_bf16(af, bfr, acc[n], 0, 0, 0);
    }
  }
  __syncthreads();

  float* epi = (float*)smem;
  #pragma unroll
  for (int n = 0; n < 3; ++n) {
    int o = wc * 48 + n * 16 + lr;
    float bo = b_off[o];
    int row = wr * 16 + lq * 4;
    #pragma unroll
    for (int r = 0; r < 4; ++r)
      epi[(row + r) * 97 + o] = acc[n][r] + bo;
  }
  __syncthreads();

  {
    int row = t & 63, head = t >> 6;
    const float* o = epi + row * 97 + head * 12;
    float ox[NP_], oy[NP_], lg[NP_];
    #pragma unroll
    for (int p = 0; p < NP_; ++p) {
      ox[p] = o[p * 3 + 0];
      oy[p] = o[p * 3 + 1];
      lg[p] = o[p * 3 + 2];
    }
    float mx = fmaxf(fmaxf(lg[0], lg[1]), fmaxf(lg[2], lg[3]));
    float e[NP_];
    float s = 0.f;
    #pragma unroll
    for (int p = 0; p < NP_; ++p) { e[p] = expf(lg[p] - mx); s += e[p]; }
    float inv = 1.f / s;

    int hw = hw0 + row;
    float wq = (float)(hw & 63);
    float hq = (float)(hw >> 6);
    size_t base = ((size_t)(b * NH_ + head) * HW_ + hw) * NP_;
    #pragma unroll
    for (int p = 0; p < NP_; ++p) {
      float wt = e[p] * inv;
      float x = wq + ox[p] * 3.15f;
      float y = hq + oy[p] * 3.15f;
      float x0f = floorf(x), y0f = floorf(y);
      int ix0 = (int)x0f, iy0 = (int)y0f;
      int ix1 = ix0 + 1, iy1 = iy0 + 1;
      float fx = x - x0f, fy = y - y0f;
      float gx0 = 1.f - fx, gy0 = 1.f - fy;

      bool vx0 = (ix0 >= 0) & (ix0 <= W_ - 1);
      bool vx1 = (ix1 >= 0) & (ix1 <= W_ - 1);
      bool vy0 = (iy0 >= 0) & (iy0 <= H_ - 1);
      bool vy1 = (iy1 >= 0) & (iy1 <= H_ - 1);
      int cx0 = min(max(ix0, 0), W_ - 1), cx1 = min(max(ix1, 0), W_ - 1);
      int cy0 = min(max(iy0, 0), H_ - 1), cy1 = min(max(iy1, 0), H_ - 1);

      float w00 = wt * gx0 * gy0 * ((vx0 & vy0) ? 1.f : 0.f);
      float w01 = wt * fx  * gy0 * ((vx1 & vy0) ? 1.f : 0.f);
      float w10 = wt * gx0 * fy  * ((vx0 & vy1) ? 1.f : 0.f);
      float w11 = wt * fx  * fy  * ((vx1 & vy1) ? 1.f : 0.f);

      __half2 h01 = __floats2half2_rn(w00, w01);
      __half2 h23 = __floats2half2_rn(w10, w11);
      uint2 pk;
      pk.x = *(u32*)&h01;
      pk.y = *(u32*)&h23;
      wpk[base + p]  = pk;
      idx4[base + p] = (u32)cx0 | ((u32)cx1 << 6) | ((u32)cy0 << 12) | ((u32)cy1 << 18);
    }
  }
}

// ---------------------------------------------------------------------------
// Kernel 2: bilinear gather, 4 channels/thread via uint2 gathers.
// Block = 4 hw x 64 threads (head = (t&63)>>3, dpq = t&7 -> dp pair 2*dpq).
// Half the gather instructions of the 2-ch version; same coalescing.
// ---------------------------------------------------------------------------
__global__ __launch_bounds__(256) void k_sample(const uint2* __restrict__ wpk,
                                                const u32* __restrict__ idx4,
                                                const uint2* __restrict__ key_t2q,
                                                uint2* __restrict__ feat2q) {
  const int t = threadIdx.x;
  const int hwid = blockIdx.x * 4 + (t >> 6);
  const int b = hwid >> 12;
  const int hw = hwid & 4095;
  const int c4 = t & 63;                 // 64 channel-quads per hw
  const int head = c4 >> 3, dpq = c4 & 7;
  const int g = b * NH_ + head;
  const size_t pbase = (((size_t)g << 12) + hw) * NP_;
  const uint2* kg = key_t2q + ((size_t)g << 15) + dpq;   // 8 uint2 per pixel

  uint2 Wp[NP_];
  u32 I[NP_];
  #pragma unroll
  for (int p = 0; p < NP_; ++p) { Wp[p] = wpk[pbase + p]; I[p] = idx4[pbase + p]; }

  uint2 v00[NP_], v01[NP_], v10[NP_], v11[NP_];
  #pragma unroll
  for (int p = 0; p < NP_; ++p) {
    u32 ip = I[p];
    int cx0 = ip & 63, cx1 = (ip >> 6) & 63, cy0 = (ip >> 12) & 63, cy1 = (ip >> 18) & 63;
    v00[p] = kg[((cy0 << 6) | cx0) * 8];
    v01[p] = kg[((cy0 << 6) | cx1) * 8];
    v10[p] = kg[((cy1 << 6) | cx0) * 8];
    v11[p] = kg[((cy1 << 6) | cx1) * 8];
  }

  float a0 = 0.f, a1 = 0.f, a2 = 0.f, a3 = 0.f;
  #pragma unroll
  for (int p = 0; p < NP_; ++p) {
    float2 w01 = __half22float2(*(const __half2*)&Wp[p].x);
    float2 w23 = __half22float2(*(const __half2*)&Wp[p].y);
    a0 = fmaf(w01.x, bflo(v00[p].x), a0);
    a0 = fmaf(w01.y, bflo(v01[p].x), a0);
    a0 = fmaf(w23.x, bflo(v10[p].x), a0);
    a0 = fmaf(w23.y, bflo(v11[p].x), a0);
    a1 = fmaf(w01.x, bfhi(v00[p].x), a1);
    a1 = fmaf(w01.y, bfhi(v01[p].x), a1);
    a1 = fmaf(w23.x, bfhi(v10[p].x), a1);
    a1 = fmaf(w23.y, bfhi(v11[p].x), a1);
    a2 = fmaf(w01.x, bflo(v00[p].y), a2);
    a2 = fmaf(w01.y, bflo(v01[p].y), a2);
    a2 = fmaf(w23.x, bflo(v10[p].y), a2);
    a2 = fmaf(w23.y, bflo(v11[p].y), a2);
    a3 = fmaf(w01.x, bfhi(v00[p].y), a3);
    a3 = fmaf(w01.y, bfhi(v01[p].y), a3);
    a3 = fmaf(w23.x, bfhi(v10[p].y), a3);
    a3 = fmaf(w23.y, bfhi(v11[p].y), a3);
  }
  uint2 o;
  o.x = (u32)f2bf(a0) | ((u32)f2bf(a1) << 16);
  o.y = (u32)f2bf(a2) | ((u32)f2bf(a3) << 16);
  feat2q[(((size_t)b * HW_ + hw) << 6) + c4] = o;
}

// ---------------------------------------------------------------------------
// Kernel 3: out = feat @ w_proj^T + b_proj, full-width (validated R14).
// ---------------------------------------------------------------------------
__global__ __launch_bounds__(256) void k_proj_mfma(const u16* __restrict__ A,
                                                   const u16* __restrict__ Bw,
                                                   const float* __restrict__ bias,
                                                   float* __restrict__ out) {
  __shared__ char smem[20480];  // A: [0,4K)  B: [4K,20K)
  const int t = threadIdx.x, l = t & 63, w = t >> 6;
  const int lr = l & 15, lq = l >> 4;
  const int r0 = blockIdx.x * 64;

  f32x4 acc[16];
  #pragma unroll
  for (int n = 0; n < 16; ++n) acc[n] = (f32x4){0.f, 0.f, 0.f, 0.f};

  for (int k0 = 0; k0 < 256; k0 += 32) {
    {
      const u16* g = A + ((size_t)(r0 + l)) * 256 + k0 + w * 8;
      __builtin_amdgcn_global_load_lds((const as1_u32*)g,
          (as3_u32*)(smem + w * 1024), 16, 0, 0);
    }
    #pragma unroll
    for (int j = 0; j < 4; ++j) {
      int i = w * 4 + j;
      int kq = i >> 2, cg = i & 3;
      const u16* g = Bw + ((size_t)(cg * 64 + l)) * 256 + k0 + kq * 8;
      __builtin_amdgcn_global_load_lds((const as1_u32*)g,
          (as3_u32*)(smem + 4096 + (kq * 256 + cg * 64) * 16), 16, 0, 0);
    }
    __syncthreads();

    bf16x8 af = *(const bf16x8*)(smem + (lq * 64 + w * 16 + lr) * 16);
    #pragma unroll
    for (int n = 0; n < 16; ++n) {
      bf16x8 bfr = *(const bf16x8*)(smem + 4096 + (lq * 256 + n * 16 + lr) * 16);
      acc[n] = __builtin_amdgcn_mfma_f32_16x16x32_bf16(af, bfr, acc[n], 0, 0, 0);
    }
    __syncthreads();
  }

  #pragma unroll
  for (int n = 0; n < 16; ++n) {
    int col = n * 16 + lr;
    float bv = bias[col];
    int row = r0 + w * 16 + lq * 4;
    #pragma unroll
    for (int r = 0; r < 4; ++r)
      out[(size_t)(row + r) * 256 + col] = acc[n][r] + bv;
  }
}

// ---------------------------------------------------------------------------
extern "C" void kernel_launch(void* const* d_in, const int* in_sizes, int n_in,
                              void* d_out, int out_size, void* d_ws, size_t ws_size,
                              hipStream_t stream) {
  const float* query  = (const float*)d_in[0];
  const float* key    = (const float*)d_in[1];
  const float* w_off  = (const float*)d_in[2];
  const float* b_off  = (const float*)d_in[3];
  const float* w_proj = (const float*)d_in[4];
  const float* b_proj = (const float*)d_in[5];
  float* out = (float*)d_out;

  char* ws = (char*)d_ws;
  uint2*  wpk      = (uint2*)ws;                                //  8 MB
  u32*    idx4     = (u32*)(ws + (size_t)8  * 1024 * 1024);     //  4 MB
  u32*    key_t2   = (u32*)(ws + (size_t)16 * 1024 * 1024);     // 16 MB
  u32*    feat2    = (u32*)(ws + (size_t)32 * 1024 * 1024);     // 16 MB
  uint2*  wproj_bf = (uint2*)(ws + (size_t)48 * 1024 * 1024);   // 128 KB

  hipLaunchKernelGGL(k_trans_conv,   dim3(4160),  dim3(256), 0, stream,
                     key, w_proj, key_t2, wproj_bf);
  hipLaunchKernelGGL(k_offsets_mfma, dim3(512),   dim3(512), 0, stream,
                     query, w_off, b_off, wpk, idx4);
  hipLaunchKernelGGL(k_sample,       dim3(8192),  dim3(256), 0, stream,
                     wpk, idx4, (const uint2*)key_t2, (uint2*)feat2);
  hipLaunchKernelGGL(k_proj_mfma,    dim3(512),   dim3(256), 0, stream,
                     (const u16*)feat2, (const u16*)wproj_bf, b_proj, out);
}